// Round 1
// baseline (1589.957 us; speedup 1.0000x reference)
//
#include <hip/hip_runtime.h>
#include <hip/hip_bf16.h>
#include <stdint.h>

// Problem constants
#define HW    65536          // 256*256
#define NB    4              // batch
#define CIN   192            // dim
#define OYC   288            // 192 q + 96 kv conv1x1 outputs
#define QP2   264            // padded LDS row stride (bf16) for conflict-free reads

// ---- bf16 helpers (bf16 bits<<16 == fp32 bits) ----
__device__ __forceinline__ float bflo(unsigned u){ return __uint_as_float(u << 16); }
__device__ __forceinline__ float bfhi(unsigned u){ return __uint_as_float(u & 0xffff0000u); }
__device__ __forceinline__ float bf2f(__hip_bfloat16 v){ return __bfloat162float(v); }

// ============================================================================
// K0: fold ln_w into transposed concat weight Wt[c][o] (o<192: q_w, else kv_w),
//     bias[o] = sum_c W[o,c]*ln_b[c]
// ============================================================================
__global__ void k_prep(const float* __restrict__ qw, const float* __restrict__ kvw,
                       const float* __restrict__ lnw, const float* __restrict__ lnb,
                       float* __restrict__ Wt, float* __restrict__ bias) {
  int t = threadIdx.x;
  for (int i = t; i < CIN * OYC; i += 256) {
    int c = i / OYC, o = i % OYC;
    float w = (o < 192) ? qw[o * 192 + c] : kvw[(o - 192) * 192 + c];
    Wt[i] = w * lnw[c];
  }
  for (int o = t; o < OYC; o += 256) {
    float s = 0.f;
    for (int c = 0; c < CIN; ++c)
      s += ((o < 192) ? qw[o * 192 + c] : kvw[(o - 192) * 192 + c]) * lnb[c];
    bias[o] = s;
  }
}

// ============================================================================
// K1: fused LayerNorm + conv1x1 (288 outputs). 64-pixel tile per block.
//     x read exactly once. y written bf16. Inner loop: wave-uniform s_loads of
//     Wt (per-wave o-range via readfirstlane), lds x reads are 2-way (free).
// ============================================================================
__global__ __launch_bounds__(256) void k_conv1(const float* __restrict__ x,
                                               const float* __restrict__ Wt,
                                               const float* __restrict__ bias,
                                               __hip_bfloat16* __restrict__ y) {
  __shared__ float lx[CIN * 64];
  __shared__ float mul[64], rsl[64];
  int bid = blockIdx.x;
  int b  = bid >> 10;             // 1024 tiles per batch
  int n0 = (bid & 1023) * 64;
  int tid = threadIdx.x;

  const float* xb = x + (size_t)b * CIN * HW + n0;
  for (int i = tid; i < CIN * 64; i += 256) {
    int c = i >> 6, tn = i & 63;
    lx[i] = xb[(size_t)c * HW + tn];
  }
  __syncthreads();
  if (tid < 64) {  // per-pixel LN stats (wave 0)
    float s = 0.f, ss = 0.f;
    for (int c = 0; c < CIN; ++c) { float v = lx[c * 64 + tid]; s += v; ss += v * v; }
    float m = s * (1.f / CIN);
    float var = ss * (1.f / CIN) - m * m;
    mul[tid] = m; rsl[tid] = rsqrtf(var + 1e-5f);
  }
  __syncthreads();
  for (int i = tid; i < CIN * 64; i += 256) {  // normalize in place (ln_w folded into Wt)
    int tn = i & 63;
    lx[i] = (lx[i] - mul[tn]) * rsl[tn];
  }
  __syncthreads();

  int wave = __builtin_amdgcn_readfirstlane(tid >> 6);  // 0..3 -> 72 outputs each
  int tn = tid & 63;
  for (int ch = 0; ch < 3; ++ch) {
    int o0 = wave * 72 + ch * 24;         // multiple of 8; never crosses the 192 boundary
    float acc[24];
#pragma unroll
    for (int j = 0; j < 24; ++j) acc[j] = 0.f;
    const float* wp = Wt + o0;
    for (int c = 0; c < CIN; ++c) {
      float xv = lx[c * 64 + tn];
#pragma unroll
      for (int j = 0; j < 24; ++j) acc[j] = fmaf(wp[c * OYC + j], xv, acc[j]);
    }
    __hip_bfloat16* yo = y + ((size_t)b * OYC + o0) * HW + n0 + tn;
#pragma unroll
    for (int j = 0; j < 24; ++j)
      yo[(size_t)j * HW] = __float2bfloat16(acc[j] + bias[o0 + j]);
  }
}

// ============================================================================
// K2: depthwise 3x3 over kv channels (y ch 192..287). 16 rows per block,
//     sliding 3-row register window. k (ch<48) also accumulates sum(k^2).
// ============================================================================
__global__ __launch_bounds__(256) void k_dwkv(const __hip_bfloat16* __restrict__ y,
                                              const float* __restrict__ kvdw,
                                              __hip_bfloat16* __restrict__ kbuf,
                                              __hip_bfloat16* __restrict__ vbuf,
                                              float* __restrict__ kss) {
  int bid = blockIdx.x;
  int hb = bid & 15;                  // 16 row-tiles
  int ck = (bid >> 4) % 96;
  int b  = bid / (16 * 96);
  int col = threadIdx.x;
  int h0 = hb * 16;

  const __hip_bfloat16* yp = y + (size_t)(b * OYC + 192 + ck) * HW;
  float w[9];
#pragma unroll
  for (int i = 0; i < 9; ++i) w[i] = kvdw[ck * 9 + i];

  auto loadrow = [&](int hh, float* r) {
    if ((unsigned)hh < 256u) {
      const __hip_bfloat16* yr = yp + hh * 256;
      r[1] = bf2f(yr[col]);
      r[0] = (col > 0)   ? bf2f(yr[col - 1]) : 0.f;
      r[2] = (col < 255) ? bf2f(yr[col + 1]) : 0.f;
    } else { r[0] = r[1] = r[2] = 0.f; }
  };

  float rm1[3], r0[3], rp1[3];
  loadrow(h0 - 1, rm1);
  loadrow(h0, r0);
  float ssq = 0.f;
  bool isk = (ck < 48);
  __hip_bfloat16* ob = (isk ? kbuf : vbuf) + (size_t)(b * 48 + (ck % 48)) * HW;
  for (int r = 0; r < 16; ++r) {
    loadrow(h0 + r + 1, rp1);
    float val = w[0]*rm1[0] + w[1]*rm1[1] + w[2]*rm1[2]
              + w[3]*r0[0]  + w[4]*r0[1]  + w[5]*r0[2]
              + w[6]*rp1[0] + w[7]*rp1[1] + w[8]*rp1[2];
    ob[(h0 + r) * 256 + col] = __float2bfloat16(val);
    if (isk) { float fv = bf2f(__float2bfloat16(val)); ssq += fv * fv; }
#pragma unroll
    for (int i = 0; i < 3; ++i) { rm1[i] = r0[i]; r0[i] = rp1[i]; }
  }
  if (isk) {  // block reduce (ck uniform per block -> uniform branch)
#pragma unroll
    for (int off = 32; off > 0; off >>= 1) ssq += __shfl_down(ssq, off);
    __shared__ float ws4[4];
    if ((threadIdx.x & 63) == 0) ws4[threadIdx.x >> 6] = ssq;
    __syncthreads();
    if (threadIdx.x == 0) atomicAdd(&kss[b * 48 + ck], ws4[0] + ws4[1] + ws4[2] + ws4[3]);
  }
}

// ============================================================================
// K3: per (b, kvh, row): dwconv q (96 ch) -> LDS (bf16, stride QP2: conflict
//     free), fused sum(q^2) and partial QK^T (3x3 register tile / thread),
//     atomicAdd into logits. q/k never hit HBM.
// ============================================================================
__global__ __launch_bounds__(256) void k_dwq_attn(const __hip_bfloat16* __restrict__ y,
                                                  const float* __restrict__ qdw,
                                                  const __hip_bfloat16* __restrict__ kbuf,
                                                  float* __restrict__ qss,
                                                  float* __restrict__ attn) {
  __shared__ __align__(16) __hip_bfloat16 ql[96 * QP2];
  __shared__ __align__(16) __hip_bfloat16 kl[24 * QP2];
  int bid = blockIdx.x;
  int h   = bid & 255;
  int kvh = (bid >> 8) & 1;
  int b   = bid >> 9;
  int tid = threadIdx.x;
  int col = tid;

  // phase 1: q dwconv row h, channels kvh*96 .. +96
  for (int cc = 0; cc < 96; ++cc) {
    int cg = kvh * 96 + cc;
    const __hip_bfloat16* yp = y + (size_t)(b * OYC + cg) * HW;
    float val = 0.f;
#pragma unroll
    for (int dy = 0; dy < 3; ++dy) {
      int yy = h + dy - 1;
      if ((unsigned)yy < 256u) {
        const __hip_bfloat16* yr = yp + yy * 256;
#pragma unroll
        for (int dx = 0; dx < 3; ++dx) {
          int xx = col + dx - 1;
          if ((unsigned)xx < 256u)
            val = fmaf(qdw[cg * 9 + dy * 3 + dx], bf2f(yr[xx]), val);
        }
      }
    }
    ql[cc * QP2 + col] = __float2bfloat16(val);
  }
  for (int d = 0; d < 24; ++d)
    kl[d * QP2 + col] = kbuf[(size_t)(b * 48 + kvh * 24 + d) * HW + h * 256 + col];
  __syncthreads();

  // sum(q^2) per channel (from the same bf16 values used in the dot)
  if (tid < 96) {
    float s = 0.f;
    for (int n = 0; n < 256; n += 8) {
      uint4 u = *(const uint4*)&ql[tid * QP2 + n];
      float f0=bflo(u.x),f1=bfhi(u.x),f2=bflo(u.y),f3=bfhi(u.y);
      float f4=bflo(u.z),f5=bfhi(u.z),f6=bflo(u.w),f7=bfhi(u.w);
      s += f0*f0+f1*f1+f2*f2+f3*f3+f4*f4+f5*f5+f6*f6+f7*f7;
    }
    atomicAdd(&qss[b * 192 + kvh * 96 + tid], s);
  }

  // phase 2: partial QK^T. thread = (ccg, dg) -> 3x3 pair tile.
  int dg = tid & 7, ccg = tid >> 3;
  int cc0 = ccg * 3, d0 = dg * 3;
  float acc[9];
#pragma unroll
  for (int i = 0; i < 9; ++i) acc[i] = 0.f;
  for (int n = 0; n < 256; n += 8) {
    float a[3][8], bv[3][8];
#pragma unroll
    for (int i = 0; i < 3; ++i) {
      uint4 u = *(const uint4*)&ql[(cc0 + i) * QP2 + n];
      a[i][0]=bflo(u.x); a[i][1]=bfhi(u.x); a[i][2]=bflo(u.y); a[i][3]=bfhi(u.y);
      a[i][4]=bflo(u.z); a[i][5]=bfhi(u.z); a[i][6]=bflo(u.w); a[i][7]=bfhi(u.w);
    }
#pragma unroll
    for (int j = 0; j < 3; ++j) {
      uint4 u = *(const uint4*)&kl[(d0 + j) * QP2 + n];
      bv[j][0]=bflo(u.x); bv[j][1]=bfhi(u.x); bv[j][2]=bflo(u.y); bv[j][3]=bfhi(u.y);
      bv[j][4]=bflo(u.z); bv[j][5]=bfhi(u.z); bv[j][6]=bflo(u.w); bv[j][7]=bfhi(u.w);
    }
#pragma unroll
    for (int i = 0; i < 3; ++i)
#pragma unroll
      for (int j = 0; j < 3; ++j)
#pragma unroll
        for (int e = 0; e < 8; ++e)
          acc[i * 3 + j] = fmaf(a[i][e], bv[j][e], acc[i * 3 + j]);
  }
#pragma unroll
  for (int i = 0; i < 3; ++i)
#pragma unroll
    for (int j = 0; j < 3; ++j) {
      int cc = cc0 + i, d = d0 + j;
      int head = kvh * 4 + cc / 24, cp = cc % 24;
      atomicAdd(&attn[(((b * 8 + head) * 24) + cp) * 24 + d], acc[i * 3 + j]);
    }
}

// ============================================================================
// K4: l2norm scaling + temperature + softmax, then fold proj_w through attn:
//     Mt[b][j=kvh*24+d][o] = sum_cc proj[o][kvh*96+cc] * attnS[kvh*96+cc][d]
// ============================================================================
__global__ void k_attn_final(const float* __restrict__ attn, const float* __restrict__ qss,
                             const float* __restrict__ kss, const float* __restrict__ temp,
                             const float* __restrict__ projw, float* __restrict__ Mt) {
  int b = blockIdx.x;
  int t = threadIdx.x;
  __shared__ float as_[96 * 25];
  float acc[48];
#pragma unroll
  for (int j = 0; j < 48; ++j) acc[j] = 0.f;
  for (int kvh = 0; kvh < 2; ++kvh) {
    __syncthreads();
    if (t < 96) {
      int row = kvh * 96 + t;           // global q channel
      int h = row / 24, cp = row % 24;
      float rq = 1.f / fmaxf(sqrtf(qss[b * 192 + row]), 1e-12f);
      float tp = temp[h];
      float lg[24]; float mx = -1e30f;
#pragma unroll
      for (int d = 0; d < 24; ++d) {
        float rk = 1.f / fmaxf(sqrtf(kss[b * 48 + kvh * 24 + d]), 1e-12f);
        float l = attn[(((b * 8 + h) * 24) + cp) * 24 + d] * rq * rk * tp;
        lg[d] = l; mx = fmaxf(mx, l);
      }
      float s = 0.f;
#pragma unroll
      for (int d = 0; d < 24; ++d) { lg[d] = __expf(lg[d] - mx); s += lg[d]; }
      float inv = 1.f / s;
#pragma unroll
      for (int d = 0; d < 24; ++d) as_[t * 25 + d] = lg[d] * inv;
    }
    __syncthreads();
    if (t < 192) {
      for (int cc = 0; cc < 96; ++cc) {
        float pw = projw[t * 192 + kvh * 96 + cc];
        const float* ar = &as_[cc * 25];
#pragma unroll
        for (int d = 0; d < 24; ++d) acc[kvh * 24 + d] = fmaf(pw, ar[d], acc[kvh * 24 + d]);
      }
    }
  }
  if (t < 192) {
#pragma unroll
    for (int j = 0; j < 48; ++j) Mt[((size_t)b * 48 + j) * 192 + t] = acc[j];
  }
}

// ============================================================================
// K5: out[b][o][n] = sum_j Mt[b][j][o] * v[b][j][n]   (fp32 output)
// ============================================================================
__global__ __launch_bounds__(256) void k_out(const __hip_bfloat16* __restrict__ vbuf,
                                             const float* __restrict__ Mt,
                                             float* __restrict__ out) {
  __shared__ float lv[48 * 64];
  int bid = blockIdx.x;
  int b  = bid >> 10;
  int n0 = (bid & 1023) * 64;
  int tid = threadIdx.x;
  const __hip_bfloat16* vb = vbuf + (size_t)b * 48 * HW + n0;
  for (int i = tid; i < 48 * 64; i += 256) {
    int c = i >> 6, tn = i & 63;
    lv[i] = bf2f(vb[(size_t)c * HW + tn]);
  }
  __syncthreads();
  int wave = __builtin_amdgcn_readfirstlane(tid >> 6);
  int tn = tid & 63;
  const float* mb = Mt + (size_t)b * 48 * 192;
  for (int ch = 0; ch < 2; ++ch) {
    int o0 = wave * 48 + ch * 24;
    float acc[24];
#pragma unroll
    for (int j = 0; j < 24; ++j) acc[j] = 0.f;
    for (int c = 0; c < 48; ++c) {
      float xv = lv[c * 64 + tn];
#pragma unroll
      for (int j = 0; j < 24; ++j) acc[j] = fmaf(mb[c * 192 + o0 + j], xv, acc[j]);
    }
    float* op = out + ((size_t)b * 192 + o0) * HW + n0 + tn;
#pragma unroll
    for (int j = 0; j < 24; ++j) op[(size_t)j * HW] = acc[j];
  }
}

// ============================================================================
// ws layout (float offsets):
//  0        qss   [4*192]      = 768
//  768      kss   [4*48]       = 192
//  960      attn  [4*8*24*24]  = 18432
//  19392    Mt    [4*48*192]   = 36864
//  56256    bias  [288]
//  56544    Wt    [192*288]    = 55296
//  111872   y   bf16 [4*288*HW]  (= 37748736 float-equivalents)
//  37860608 kbuf bf16 [4*48*HW]  (= 6291456)
//  44152064 vbuf bf16 [4*48*HW]  (= 6291456)
//  total ~202 MB
// ============================================================================
extern "C" void kernel_launch(void* const* d_in, const int* in_sizes, int n_in,
                              void* d_out, int out_size, void* d_ws, size_t ws_size,
                              hipStream_t stream) {
  const float* x     = (const float*)d_in[0];
  const float* ln_w  = (const float*)d_in[1];
  const float* ln_b  = (const float*)d_in[2];
  const float* q_w   = (const float*)d_in[3];
  const float* q_dw  = (const float*)d_in[4];
  const float* kv_w  = (const float*)d_in[5];
  const float* kv_dw = (const float*)d_in[6];
  const float* projw = (const float*)d_in[7];
  const float* temp  = (const float*)d_in[8];
  float* out = (float*)d_out;
  float* wsf = (float*)d_ws;

  float* qss  = wsf;
  float* kss  = wsf + 768;
  float* attn = wsf + 960;
  float* Mt   = wsf + 19392;
  float* bias = wsf + 56256;
  float* Wt   = wsf + 56544;
  __hip_bfloat16* y    = (__hip_bfloat16*)(wsf + 111872);
  __hip_bfloat16* kbuf = (__hip_bfloat16*)(wsf + 37860608);
  __hip_bfloat16* vbuf = (__hip_bfloat16*)(wsf + 44152064);

  hipMemsetAsync(wsf, 0, 19392 * sizeof(float), stream);  // qss+kss+attn accumulators
  hipLaunchKernelGGL(k_prep, dim3(1), dim3(256), 0, stream, q_w, kv_w, ln_w, ln_b, Wt, bias);
  hipLaunchKernelGGL(k_conv1, dim3(NB * 1024), dim3(256), 0, stream, x, Wt, bias, y);
  hipLaunchKernelGGL(k_dwkv, dim3(NB * 96 * 16), dim3(256), 0, stream, y, kv_dw, kbuf, vbuf, kss);
  hipLaunchKernelGGL(k_dwq_attn, dim3(NB * 2 * 256), dim3(256), 0, stream, y, q_dw, kbuf, qss, attn);
  hipLaunchKernelGGL(k_attn_final, dim3(NB), dim3(256), 0, stream, attn, qss, kss, temp, projw, Mt);
  hipLaunchKernelGGL(k_out, dim3(NB * 1024), dim3(256), 0, stream, vbuf, Mt, out);
}

// Round 2
// 1206.671 us; speedup vs baseline: 1.3176x; 1.3176x over previous
//
#include <hip/hip_runtime.h>
#include <hip/hip_bf16.h>
#include <stdint.h>

// Problem constants
#define HW    65536          // 256*256
#define NB    4              // batch
#define CIN   192            // dim
#define OYC   288            // 192 q + 96 kv conv1x1 outputs
#define QP2   264            // padded LDS row stride (bf16) for conflict-free QK reads

// ---- bf16 helpers (bf16 bits<<16 == fp32 bits) ----
__device__ __forceinline__ float bflo(unsigned u){ return __uint_as_float(u << 16); }
__device__ __forceinline__ float bfhi(unsigned u){ return __uint_as_float(u & 0xffff0000u); }
__device__ __forceinline__ float bf2f(__hip_bfloat16 v){ return __bfloat162float(v); }

__device__ __forceinline__ void unpack8(uint4 u, float* f) {
  f[0]=bflo(u.x); f[1]=bfhi(u.x); f[2]=bflo(u.y); f[3]=bfhi(u.y);
  f[4]=bflo(u.z); f[5]=bfhi(u.z); f[6]=bflo(u.w); f[7]=bfhi(u.w);
}

union BF8 { uint4 u; __hip_bfloat16 h[8]; };

// ============================================================================
// K0: fold ln_w into transposed concat weight Wt[c][o] (o<192: q_w, else kv_w),
//     bias[o] = sum_c W[o,c]*ln_b[c]
// ============================================================================
__global__ void k_prep(const float* __restrict__ qw, const float* __restrict__ kvw,
                       const float* __restrict__ lnw, const float* __restrict__ lnb,
                       float* __restrict__ Wt, float* __restrict__ bias) {
  int t = threadIdx.x;
  for (int i = t; i < CIN * OYC; i += 256) {
    int c = i / OYC, o = i % OYC;
    float w = (o < 192) ? qw[o * 192 + c] : kvw[(o - 192) * 192 + c];
    Wt[i] = w * lnw[c];
  }
  for (int o = t; o < OYC; o += 256) {
    float s = 0.f;
    for (int c = 0; c < CIN; ++c)
      s += ((o < 192) ? qw[o * 192 + c] : kvw[(o - 192) * 192 + c]) * lnb[c];
    bias[o] = s;
  }
}

// ============================================================================
// K1: fused LayerNorm + conv1x1 (288 outputs). 64-pixel tile per block.
// ============================================================================
__global__ __launch_bounds__(256) void k_conv1(const float* __restrict__ x,
                                               const float* __restrict__ Wt,
                                               const float* __restrict__ bias,
                                               __hip_bfloat16* __restrict__ y) {
  __shared__ float lx[CIN * 64];
  __shared__ float mul[64], rsl[64];
  int bid = blockIdx.x;
  int b  = bid >> 10;             // 1024 tiles per batch
  int n0 = (bid & 1023) * 64;
  int tid = threadIdx.x;

  const float* xb = x + (size_t)b * CIN * HW + n0;
  for (int i = tid; i < CIN * 64; i += 256) {
    int c = i >> 6, tn = i & 63;
    lx[i] = xb[(size_t)c * HW + tn];
  }
  __syncthreads();
  if (tid < 64) {  // per-pixel LN stats (wave 0)
    float s = 0.f, ss = 0.f;
    for (int c = 0; c < CIN; ++c) { float v = lx[c * 64 + tid]; s += v; ss += v * v; }
    float m = s * (1.f / CIN);
    float var = ss * (1.f / CIN) - m * m;
    mul[tid] = m; rsl[tid] = rsqrtf(var + 1e-5f);
  }
  __syncthreads();
  for (int i = tid; i < CIN * 64; i += 256) {  // normalize in place
    int tn = i & 63;
    lx[i] = (lx[i] - mul[tn]) * rsl[tn];
  }
  __syncthreads();

  int wave = __builtin_amdgcn_readfirstlane(tid >> 6);  // 0..3 -> 72 outputs each
  int tn = tid & 63;
  for (int ch = 0; ch < 3; ++ch) {
    int o0 = wave * 72 + ch * 24;
    float acc[24];
#pragma unroll
    for (int j = 0; j < 24; ++j) acc[j] = 0.f;
    const float* wp = Wt + o0;
    for (int c = 0; c < CIN; ++c) {
      float xv = lx[c * 64 + tn];
#pragma unroll
      for (int j = 0; j < 24; ++j) acc[j] = fmaf(wp[c * OYC + j], xv, acc[j]);
    }
    __hip_bfloat16* yo = y + ((size_t)b * OYC + o0) * HW + n0 + tn;
#pragma unroll
    for (int j = 0; j < 24; ++j)
      yo[(size_t)j * HW] = __float2bfloat16(acc[j] + bias[o0 + j]);
  }
}

// ============================================================================
// K2: depthwise 3x3 over kv channels. Block = (b, ch, 16-row tile).
//     18 rows staged in LDS via uint4; thread = (rowpair, colgroup-of-8).
// ============================================================================
__global__ __launch_bounds__(256) void k_dwkv(const __hip_bfloat16* __restrict__ y,
                                              const float* __restrict__ kvdw,
                                              __hip_bfloat16* __restrict__ kbuf,
                                              __hip_bfloat16* __restrict__ vbuf,
                                              float* __restrict__ kss) {
  __shared__ __align__(16) __hip_bfloat16 stage[18 * 256];
  int bid = blockIdx.x;
  int hb = bid & 15;                  // 16 row-tiles
  int ck = (bid >> 4) % 96;
  int b  = bid / (16 * 96);
  int tid = threadIdx.x;
  int h0 = hb * 16;

  const __hip_bfloat16* yp = y + (size_t)(b * OYC + 192 + ck) * HW;
  for (int i = tid; i < 18 * 32; i += 256) {
    int ry = i >> 5, seg = i & 31;
    int hh = h0 - 1 + ry;
    uint4 u = make_uint4(0u, 0u, 0u, 0u);
    if ((unsigned)hh < 256u) u = *(const uint4*)(yp + hh * 256 + seg * 8);
    *(uint4*)&stage[ry * 256 + seg * 8] = u;
  }
  __syncthreads();

  float w[9];
#pragma unroll
  for (int i = 0; i < 9; ++i) w[i] = kvdw[ck * 9 + i];

  int cg = tid & 31, rg = tid >> 5;   // 8 rowpairs x 32 colgroups
  int c0 = cg * 8;
  bool isk = (ck < 48);
  __hip_bfloat16* ob = (isk ? kbuf : vbuf) + (size_t)(b * 48 + (ck % 48)) * HW;
  float ssq = 0.f;
#pragma unroll
  for (int rr = 0; rr < 2; ++rr) {
    int orow = rg * 2 + rr;
    float o[8];
#pragma unroll
    for (int j = 0; j < 8; ++j) o[j] = 0.f;
#pragma unroll
    for (int ry = 0; ry < 3; ++ry) {
      const __hip_bfloat16* rb = &stage[(orow + ry) * 256];
      float v[8];
      unpack8(*(const uint4*)&rb[c0], v);
      float vl = (c0 > 0)       ? bf2f(rb[c0 - 1]) : 0.f;
      float vr = (c0 + 8 < 256) ? bf2f(rb[c0 + 8]) : 0.f;
      float wl = w[ry * 3], wm = w[ry * 3 + 1], wr = w[ry * 3 + 2];
      o[0] = fmaf(wl, vl, fmaf(wm, v[0], fmaf(wr, v[1], o[0])));
#pragma unroll
      for (int j = 1; j < 7; ++j)
        o[j] = fmaf(wl, v[j-1], fmaf(wm, v[j], fmaf(wr, v[j+1], o[j])));
      o[7] = fmaf(wl, v[6], fmaf(wm, v[7], fmaf(wr, vr, o[7])));
    }
    BF8 t;
#pragma unroll
    for (int j = 0; j < 8; ++j) {
      t.h[j] = __float2bfloat16(o[j]);
      if (isk) { float fv = bf2f(t.h[j]); ssq += fv * fv; }
    }
    *(uint4*)(ob + (size_t)(h0 + orow) * 256 + c0) = t.u;
  }
  if (isk) {
#pragma unroll
    for (int off = 32; off > 0; off >>= 1) ssq += __shfl_down(ssq, off);
    __shared__ float ws4[4];
    if ((tid & 63) == 0) ws4[tid >> 6] = ssq;
    __syncthreads();
    if (tid == 0) atomicAdd(&kss[b * 48 + ck], ws4[0] + ws4[1] + ws4[2] + ws4[3]);
  }
}

// ============================================================================
// K3: per (b, kvh, qhalf, row): staged dwconv of 48 q channels -> ql (LDS),
//     fused sum(q^2) and partial QK^T (3x3 tile, n split in 2 halves),
//     in-block nhalf reduction, then atomicAdd into logits.
//     q never hits HBM. LDS = 12288(kl) + 25344(ql) + 18432(stage) + 4608(red)
// ============================================================================
__global__ __launch_bounds__(256) void k_dwq_attn(const __hip_bfloat16* __restrict__ y,
                                                  const float* __restrict__ qdw,
                                                  const __hip_bfloat16* __restrict__ kbuf,
                                                  float* __restrict__ qss,
                                                  float* __restrict__ attn) {
  __shared__ __align__(16) __hip_bfloat16 kl[24 * 256];
  __shared__ __align__(16) __hip_bfloat16 ql[48 * QP2];
  __shared__ __align__(16) __hip_bfloat16 stage[12 * 3 * 256];
  __shared__ float red[128 * 9];

  int bid = blockIdx.x;
  int h   = bid & 255;
  int qh  = (bid >> 8) & 1;
  int kvh = (bid >> 9) & 1;
  int b   = bid >> 10;
  int tid = threadIdx.x;

  // load k tile (24 rows x 256 cols)
  const __hip_bfloat16* kp = kbuf + (size_t)(b * 48 + kvh * 24) * HW + h * 256;
  for (int i = tid; i < 24 * 32; i += 256) {
    int d = i >> 5, seg = i & 31;
    *(uint4*)&kl[d * 256 + seg * 8] = *(const uint4*)(kp + (size_t)d * HW + seg * 8);
  }

  // dwconv 48 channels in 4 chunks of 12
  for (int chunk = 0; chunk < 4; ++chunk) {
    __syncthreads();   // protect stage from previous chunk's readers
    for (int i = tid; i < 12 * 3 * 32; i += 256) {
      int seg = i & 31, rr = i >> 5;
      int ch = rr / 3, ry = rr % 3;
      int cg = kvh * 96 + qh * 48 + chunk * 12 + ch;
      int hh = h + ry - 1;
      uint4 u = make_uint4(0u, 0u, 0u, 0u);
      if ((unsigned)hh < 256u)
        u = *(const uint4*)(y + (size_t)(b * OYC + cg) * HW + hh * 256 + seg * 8);
      *(uint4*)&stage[(ch * 3 + ry) * 256 + seg * 8] = u;
    }
    __syncthreads();
    // 384 units = 12 ch x 32 colgroups; 8 output pixels per unit
    for (int i = tid; i < 384; i += 256) {
      int ch = i >> 5, cg = i & 31;
      int c0 = cg * 8;
      int cgl = kvh * 96 + qh * 48 + chunk * 12 + ch;
      const float* wp = qdw + cgl * 9;
      float o[8];
#pragma unroll
      for (int j = 0; j < 8; ++j) o[j] = 0.f;
#pragma unroll
      for (int ry = 0; ry < 3; ++ry) {
        const __hip_bfloat16* rb = &stage[(ch * 3 + ry) * 256];
        float v[8];
        unpack8(*(const uint4*)&rb[c0], v);
        float vl = (c0 > 0)       ? bf2f(rb[c0 - 1]) : 0.f;
        float vr = (c0 + 8 < 256) ? bf2f(rb[c0 + 8]) : 0.f;
        float wl = wp[ry * 3], wm = wp[ry * 3 + 1], wr = wp[ry * 3 + 2];
        o[0] = fmaf(wl, vl, fmaf(wm, v[0], fmaf(wr, v[1], o[0])));
#pragma unroll
        for (int j = 1; j < 7; ++j)
          o[j] = fmaf(wl, v[j-1], fmaf(wm, v[j], fmaf(wr, v[j+1], o[j])));
        o[7] = fmaf(wl, v[6], fmaf(wm, v[7], fmaf(wr, vr, o[7])));
      }
      BF8 t;
#pragma unroll
      for (int j = 0; j < 8; ++j) t.h[j] = __float2bfloat16(o[j]);
      *(uint4*)&ql[(chunk * 12 + ch) * QP2 + c0] = t.u;
    }
  }
  __syncthreads();   // ql + kl complete

  // sum(q^2) per channel (48 threads; others proceed to QK)
  if (tid < 48) {
    float s = 0.f;
    for (int n = 0; n < 256; n += 8) {
      float f[8];
      unpack8(*(const uint4*)&ql[tid * QP2 + n], f);
#pragma unroll
      for (int e = 0; e < 8; ++e) s += f[e] * f[e];
    }
    atomicAdd(&qss[b * 192 + kvh * 96 + qh * 48 + tid], s);
  }

  // QK^T partials: thread = (nhalf, ccg(16) x dg(8)) -> 3x3 tile over 128 n
  int nhalf = tid >> 7, r = tid & 127;
  int ccg = r >> 3, dg = r & 7;
  int cc0 = ccg * 3, d0 = dg * 3;
  float acc[9];
#pragma unroll
  for (int i = 0; i < 9; ++i) acc[i] = 0.f;
  for (int n = nhalf * 128; n < nhalf * 128 + 128; n += 8) {
    float a[3][8], bv[3][8];
#pragma unroll
    for (int i = 0; i < 3; ++i) unpack8(*(const uint4*)&ql[(cc0 + i) * QP2 + n], a[i]);
#pragma unroll
    for (int j = 0; j < 3; ++j) unpack8(*(const uint4*)&kl[(d0 + j) * 256 + n], bv[j]);
#pragma unroll
    for (int i = 0; i < 3; ++i)
#pragma unroll
      for (int j = 0; j < 3; ++j)
#pragma unroll
        for (int e = 0; e < 8; ++e)
          acc[i * 3 + j] = fmaf(a[i][e], bv[j][e], acc[i * 3 + j]);
  }
  if (nhalf == 1) {
#pragma unroll
    for (int i = 0; i < 9; ++i) red[r * 9 + i] = acc[i];
  }
  __syncthreads();
  if (nhalf == 0) {
#pragma unroll
    for (int i = 0; i < 9; ++i) acc[i] += red[r * 9 + i];
#pragma unroll
    for (int i = 0; i < 3; ++i)
#pragma unroll
      for (int j = 0; j < 3; ++j) {
        int cc = qh * 48 + cc0 + i, d = d0 + j;
        int head = kvh * 4 + cc / 24, cp = cc % 24;
        atomicAdd(&attn[(((b * 8 + head) * 24) + cp) * 24 + d], acc[i * 3 + j]);
      }
  }
}

// ============================================================================
// K4: l2norm scaling + temperature + softmax, then fold proj_w through attn:
//     Mt[b][j=kvh*24+d][o] = sum_cc proj[o][kvh*96+cc] * attnS[kvh*96+cc][d]
// ============================================================================
__global__ void k_attn_final(const float* __restrict__ attn, const float* __restrict__ qss,
                             const float* __restrict__ kss, const float* __restrict__ temp,
                             const float* __restrict__ projw, float* __restrict__ Mt) {
  int b = blockIdx.x;
  int t = threadIdx.x;
  __shared__ float as_[96 * 25];
  float acc[48];
#pragma unroll
  for (int j = 0; j < 48; ++j) acc[j] = 0.f;
  for (int kvh = 0; kvh < 2; ++kvh) {
    __syncthreads();
    if (t < 96) {
      int row = kvh * 96 + t;           // global q channel
      int h = row / 24, cp = row % 24;
      float rq = 1.f / fmaxf(sqrtf(qss[b * 192 + row]), 1e-12f);
      float tp = temp[h];
      float lg[24]; float mx = -1e30f;
#pragma unroll
      for (int d = 0; d < 24; ++d) {
        float rk = 1.f / fmaxf(sqrtf(kss[b * 48 + kvh * 24 + d]), 1e-12f);
        float l = attn[(((b * 8 + h) * 24) + cp) * 24 + d] * rq * rk * tp;
        lg[d] = l; mx = fmaxf(mx, l);
      }
      float s = 0.f;
#pragma unroll
      for (int d = 0; d < 24; ++d) { lg[d] = __expf(lg[d] - mx); s += lg[d]; }
      float inv = 1.f / s;
#pragma unroll
      for (int d = 0; d < 24; ++d) as_[t * 25 + d] = lg[d] * inv;
    }
    __syncthreads();
    if (t < 192) {
      for (int cc = 0; cc < 96; ++cc) {
        float pw = projw[t * 192 + kvh * 96 + cc];
        const float* ar = &as_[cc * 25];
#pragma unroll
        for (int d = 0; d < 24; ++d) acc[kvh * 24 + d] = fmaf(pw, ar[d], acc[kvh * 24 + d]);
      }
    }
  }
  if (t < 192) {
#pragma unroll
    for (int j = 0; j < 48; ++j) Mt[((size_t)b * 48 + j) * 192 + t] = acc[j];
  }
}

// ============================================================================
// K5: out[b][o][n] = sum_j Mt[b][j][o] * v[b][j][n]   (fp32 output)
// ============================================================================
__global__ __launch_bounds__(256) void k_out(const __hip_bfloat16* __restrict__ vbuf,
                                             const float* __restrict__ Mt,
                                             float* __restrict__ out) {
  __shared__ float lv[48 * 64];
  int bid = blockIdx.x;
  int b  = bid >> 10;
  int n0 = (bid & 1023) * 64;
  int tid = threadIdx.x;
  const __hip_bfloat16* vb = vbuf + (size_t)b * 48 * HW + n0;
  for (int i = tid; i < 48 * 64; i += 256) {
    int c = i >> 6, tn = i & 63;
    lv[i] = bf2f(vb[(size_t)c * HW + tn]);
  }
  __syncthreads();
  int wave = __builtin_amdgcn_readfirstlane(tid >> 6);
  int tn = tid & 63;
  const float* mb = Mt + (size_t)b * 48 * 192;
  for (int ch = 0; ch < 2; ++ch) {
    int o0 = wave * 48 + ch * 24;
    float acc[24];
#pragma unroll
    for (int j = 0; j < 24; ++j) acc[j] = 0.f;
    for (int c = 0; c < 48; ++c) {
      float xv = lv[c * 64 + tn];
#pragma unroll
      for (int j = 0; j < 24; ++j) acc[j] = fmaf(mb[c * 192 + o0 + j], xv, acc[j]);
    }
    float* op = out + ((size_t)b * 192 + o0) * HW + n0 + tn;
#pragma unroll
    for (int j = 0; j < 24; ++j) op[(size_t)j * HW] = acc[j];
  }
}

// ============================================================================
// ws layout (float offsets):
//  0        qss   [4*192]      = 768
//  768      kss   [4*48]       = 192
//  960      attn  [4*8*24*24]  = 18432
//  19392    Mt    [4*48*192]   = 36864
//  56256    bias  [288]
//  56544    Wt    [192*288]    = 55296
//  111872   y   bf16 [4*288*HW]
//  37860608 kbuf bf16 [4*48*HW]
//  44152064 vbuf bf16 [4*48*HW]
// ============================================================================
extern "C" void kernel_launch(void* const* d_in, const int* in_sizes, int n_in,
                              void* d_out, int out_size, void* d_ws, size_t ws_size,
                              hipStream_t stream) {
  const float* x     = (const float*)d_in[0];
  const float* ln_w  = (const float*)d_in[1];
  const float* ln_b  = (const float*)d_in[2];
  const float* q_w   = (const float*)d_in[3];
  const float* q_dw  = (const float*)d_in[4];
  const float* kv_w  = (const float*)d_in[5];
  const float* kv_dw = (const float*)d_in[6];
  const float* projw = (const float*)d_in[7];
  const float* temp  = (const float*)d_in[8];
  float* out = (float*)d_out;
  float* wsf = (float*)d_ws;

  float* qss  = wsf;
  float* kss  = wsf + 768;
  float* attn = wsf + 960;
  float* Mt   = wsf + 19392;
  float* bias = wsf + 56256;
  float* Wt   = wsf + 56544;
  __hip_bfloat16* y    = (__hip_bfloat16*)(wsf + 111872);
  __hip_bfloat16* kbuf = (__hip_bfloat16*)(wsf + 37860608);
  __hip_bfloat16* vbuf = (__hip_bfloat16*)(wsf + 44152064);

  hipMemsetAsync(wsf, 0, 19392 * sizeof(float), stream);  // qss+kss+attn accumulators
  hipLaunchKernelGGL(k_prep, dim3(1), dim3(256), 0, stream, q_w, kv_w, ln_w, ln_b, Wt, bias);
  hipLaunchKernelGGL(k_conv1, dim3(NB * 1024), dim3(256), 0, stream, x, Wt, bias, y);
  hipLaunchKernelGGL(k_dwkv, dim3(NB * 96 * 16), dim3(256), 0, stream, y, kv_dw, kbuf, vbuf, kss);
  hipLaunchKernelGGL(k_dwq_attn, dim3(NB * 2 * 2 * 256), dim3(256), 0, stream, y, q_dw, kbuf, qss, attn);
  hipLaunchKernelGGL(k_attn_final, dim3(NB), dim3(256), 0, stream, attn, qss, kss, temp, projw, Mt);
  hipLaunchKernelGGL(k_out, dim3(NB * 1024), dim3(256), 0, stream, vbuf, Mt, out);
}

// Round 3
// 920.405 us; speedup vs baseline: 1.7275x; 1.3110x over previous
//
#include <hip/hip_runtime.h>
#include <hip/hip_bf16.h>
#include <stdint.h>

// Problem constants
#define HW    65536          // 256*256
#define NB    4              // batch
#define CIN   192            // dim
#define OYC   288            // 192 q + 96 kv conv1x1 outputs
#define QP2   264            // padded LDS row stride (bf16) for conflict-free QK reads
#define BSTR  200            // B-tile LDS row stride (bf16): 100 words -> 4-bank lane shift

// ---- bf16 helpers (bf16 bits<<16 == fp32 bits) ----
__device__ __forceinline__ float bflo(unsigned u){ return __uint_as_float(u << 16); }
__device__ __forceinline__ float bfhi(unsigned u){ return __uint_as_float(u & 0xffff0000u); }
__device__ __forceinline__ float bf2f(__hip_bfloat16 v){ return __bfloat162float(v); }
__device__ __forceinline__ unsigned short f2bfbits(float f){
  __hip_bfloat16 h = __float2bfloat16(f); return *(unsigned short*)&h;
}

__device__ __forceinline__ void unpack8(uint4 u, float* f) {
  f[0]=bflo(u.x); f[1]=bfhi(u.x); f[2]=bflo(u.y); f[3]=bfhi(u.y);
  f[4]=bflo(u.z); f[5]=bfhi(u.z); f[6]=bflo(u.w); f[7]=bfhi(u.w);
}

union BF8 { uint4 u; __hip_bfloat16 h[8]; };

typedef __attribute__((ext_vector_type(8))) short short8;
typedef __attribute__((ext_vector_type(4))) float floatx4;

// ============================================================================
// K0: fold ln_w into W, emit A in MFMA-fragment order (bf16) + bias.
// AF[((ot*6+ks)*64 + lane)*8 + j] = W[ot*16 + (lane&15)][ks*32 + (lane>>4)*8 + j]
// ============================================================================
__global__ void k_prep(const float* __restrict__ qw, const float* __restrict__ kvw,
                       const float* __restrict__ lnw, const float* __restrict__ lnb,
                       __hip_bfloat16* __restrict__ AF, float* __restrict__ bias) {
  int t = threadIdx.x;
  for (int i = t; i < OYC * CIN; i += 256) {
    int o = i / CIN, c = i % CIN;
    float w = (o < 192) ? qw[o * 192 + c] : kvw[(o - 192) * 192 + c];
    float val = w * lnw[c];
    int ot = o >> 4, lo = o & 15;
    int ks = c >> 5, cr = c & 31, q = cr >> 3, j = cr & 7;
    int dst = (((ot * 6 + ks) * 64) + q * 16 + lo) * 8 + j;
    AF[dst] = __float2bfloat16(val);
  }
  for (int o = t; o < OYC; o += 256) {
    float s = 0.f;
    for (int c = 0; c < CIN; ++c)
      s += ((o < 192) ? qw[o * 192 + c] : kvw[(o - 192) * 192 + c]) * lnb[c];
    bias[o] = s;
  }
}

// ============================================================================
// K1: fused LayerNorm + conv1x1 via bf16 MFMA 16x16x32.
//     Block = 64 pixels x all 288 outputs (x read once). Waves: wo = o-half
//     (144 rows = 9 tiles), wn = px-half (32 = 2 subtiles). A frags streamed
//     from L2 (fragment-ordered global), B tile in LDS.
// ============================================================================
__global__ __launch_bounds__(256, 4) void k_conv1(const float* __restrict__ x,
                                                  const __hip_bfloat16* __restrict__ AF,
                                                  const float* __restrict__ bias,
                                                  __hip_bfloat16* __restrict__ y) {
  __shared__ __align__(16) __hip_bfloat16 Bl[64 * BSTR];
  __shared__ float part[4][64][2];
  __shared__ float murs[64][2];
  __shared__ float biasl[OYC];
  int bid = blockIdx.x;
  int b  = bid >> 10;
  int n0 = (bid & 1023) * 64;
  int tid = threadIdx.x;
  int p = tid & 63, g = tid >> 6;

  for (int i = tid; i < OYC; i += 256) biasl[i] = bias[i];

  // phase 1: load 48 channels of pixel p into regs (coalesced), LN stats
  const float* xb = x + (size_t)(b * CIN + g * 48) * HW + n0 + p;
  float xv[48];
  float s = 0.f, ss = 0.f;
#pragma unroll
  for (int j = 0; j < 48; ++j) {
    float v = xb[(size_t)j * HW];
    xv[j] = v; s += v; ss += v * v;
  }
  part[g][p][0] = s; part[g][p][1] = ss;
  __syncthreads();
  if (tid < 64) {
    float s0 = 0.f, s1 = 0.f;
#pragma unroll
    for (int gg = 0; gg < 4; ++gg) { s0 += part[gg][tid][0]; s1 += part[gg][tid][1]; }
    float m = s0 * (1.f / CIN);
    float var = s1 * (1.f / CIN) - m * m;
    murs[tid][0] = m; murs[tid][1] = rsqrtf(var + 1e-5f);
  }
  __syncthreads();
  float mu = murs[p][0], rs = murs[p][1];
#pragma unroll
  for (int j = 0; j < 48; j += 2) {
    unsigned lo = f2bfbits((xv[j]     - mu) * rs);
    unsigned hi = f2bfbits((xv[j + 1] - mu) * rs);
    *(unsigned*)&Bl[p * BSTR + g * 48 + j] = lo | (hi << 16);
  }
  __syncthreads();

  // phase 2: MFMA. wave wo owns o rows [wo*144, +144) = 9 tiles; wn owns px half.
  int wave = tid >> 6, lane = tid & 63;
  int wo = wave >> 1, wn = wave & 1;
  int li = lane & 15, q = lane >> 4;

  floatx4 acc[9][2];
#pragma unroll
  for (int t = 0; t < 9; ++t)
#pragma unroll
    for (int nt = 0; nt < 2; ++nt) acc[t][nt] = (floatx4){0.f, 0.f, 0.f, 0.f};

  for (int ks = 0; ks < 6; ++ks) {
    short8 bf[2];
#pragma unroll
    for (int nt = 0; nt < 2; ++nt) {
      int pp = wn * 32 + nt * 16 + li;
      bf[nt] = *(const short8*)&Bl[pp * BSTR + ks * 32 + q * 8];
    }
    const __hip_bfloat16* ap = AF + (((wo * 9) * 6 + ks) * 64 + lane) * 8;
#pragma unroll
    for (int t = 0; t < 9; ++t) {
      short8 af = *(const short8*)(ap + t * 6 * 64 * 8);
      acc[t][0] = __builtin_amdgcn_mfma_f32_16x16x32_bf16(af, bf[0], acc[t][0], 0, 0, 0);
      acc[t][1] = __builtin_amdgcn_mfma_f32_16x16x32_bf16(af, bf[1], acc[t][1], 0, 0, 0);
    }
  }

  // epilogue: D row = q*4+r, col = li
#pragma unroll
  for (int t = 0; t < 9; ++t) {
#pragma unroll
    for (int nt = 0; nt < 2; ++nt) {
#pragma unroll
      for (int r = 0; r < 4; ++r) {
        int o = (wo * 9 + t) * 16 + q * 4 + r;
        int pp = wn * 32 + nt * 16 + li;
        y[(size_t)(b * OYC + o) * HW + n0 + pp] = __float2bfloat16(acc[t][nt][r] + biasl[o]);
      }
    }
  }
}

// ============================================================================
// K2: depthwise 3x3 over kv channels. Block = (b, ch, 16-row tile).
// ============================================================================
__global__ __launch_bounds__(256) void k_dwkv(const __hip_bfloat16* __restrict__ y,
                                              const float* __restrict__ kvdw,
                                              __hip_bfloat16* __restrict__ kbuf,
                                              __hip_bfloat16* __restrict__ vbuf,
                                              float* __restrict__ kss) {
  __shared__ __align__(16) __hip_bfloat16 stage[18 * 256];
  int bid = blockIdx.x;
  int hb = bid & 15;                  // 16 row-tiles
  int ck = (bid >> 4) % 96;
  int b  = bid / (16 * 96);
  int tid = threadIdx.x;
  int h0 = hb * 16;

  const __hip_bfloat16* yp = y + (size_t)(b * OYC + 192 + ck) * HW;
  for (int i = tid; i < 18 * 32; i += 256) {
    int ry = i >> 5, seg = i & 31;
    int hh = h0 - 1 + ry;
    uint4 u = make_uint4(0u, 0u, 0u, 0u);
    if ((unsigned)hh < 256u) u = *(const uint4*)(yp + hh * 256 + seg * 8);
    *(uint4*)&stage[ry * 256 + seg * 8] = u;
  }
  __syncthreads();

  float w[9];
#pragma unroll
  for (int i = 0; i < 9; ++i) w[i] = kvdw[ck * 9 + i];

  int cg = tid & 31, rg = tid >> 5;   // 8 rowpairs x 32 colgroups
  int c0 = cg * 8;
  bool isk = (ck < 48);
  __hip_bfloat16* ob = (isk ? kbuf : vbuf) + (size_t)(b * 48 + (ck % 48)) * HW;
  float ssq = 0.f;
#pragma unroll
  for (int rr = 0; rr < 2; ++rr) {
    int orow = rg * 2 + rr;
    float o[8];
#pragma unroll
    for (int j = 0; j < 8; ++j) o[j] = 0.f;
#pragma unroll
    for (int ry = 0; ry < 3; ++ry) {
      const __hip_bfloat16* rb = &stage[(orow + ry) * 256];
      float v[8];
      unpack8(*(const uint4*)&rb[c0], v);
      float vl = (c0 > 0)       ? bf2f(rb[c0 - 1]) : 0.f;
      float vr = (c0 + 8 < 256) ? bf2f(rb[c0 + 8]) : 0.f;
      float wl = w[ry * 3], wm = w[ry * 3 + 1], wr = w[ry * 3 + 2];
      o[0] = fmaf(wl, vl, fmaf(wm, v[0], fmaf(wr, v[1], o[0])));
#pragma unroll
      for (int j = 1; j < 7; ++j)
        o[j] = fmaf(wl, v[j-1], fmaf(wm, v[j], fmaf(wr, v[j+1], o[j])));
      o[7] = fmaf(wl, v[6], fmaf(wm, v[7], fmaf(wr, vr, o[7])));
    }
    BF8 t;
#pragma unroll
    for (int j = 0; j < 8; ++j) {
      t.h[j] = __float2bfloat16(o[j]);
      if (isk) { float fv = bf2f(t.h[j]); ssq += fv * fv; }
    }
    *(uint4*)(ob + (size_t)(h0 + orow) * 256 + c0) = t.u;
  }
  if (isk) {
#pragma unroll
    for (int off = 32; off > 0; off >>= 1) ssq += __shfl_down(ssq, off);
    __shared__ float ws4[4];
    if ((tid & 63) == 0) ws4[tid >> 6] = ssq;
    __syncthreads();
    if (tid == 0) atomicAdd(&kss[b * 48 + ck], ws4[0] + ws4[1] + ws4[2] + ws4[3]);
  }
}

// ============================================================================
// K3: per (b, kvh, qhalf, row): staged dwconv of 48 q channels -> ql (LDS),
//     fused sum(q^2) and partial QK^T, in-block reduce, atomicAdd logits.
// ============================================================================
__global__ __launch_bounds__(256) void k_dwq_attn(const __hip_bfloat16* __restrict__ y,
                                                  const float* __restrict__ qdw,
                                                  const __hip_bfloat16* __restrict__ kbuf,
                                                  float* __restrict__ qss,
                                                  float* __restrict__ attn) {
  __shared__ __align__(16) __hip_bfloat16 kl[24 * 256];
  __shared__ __align__(16) __hip_bfloat16 ql[48 * QP2];
  __shared__ __align__(16) __hip_bfloat16 stage[12 * 3 * 256];
  __shared__ float red[128 * 9];

  int bid = blockIdx.x;
  int h   = bid & 255;
  int qh  = (bid >> 8) & 1;
  int kvh = (bid >> 9) & 1;
  int b   = bid >> 10;
  int tid = threadIdx.x;

  // load k tile (24 rows x 256 cols)
  const __hip_bfloat16* kp = kbuf + (size_t)(b * 48 + kvh * 24) * HW + h * 256;
  for (int i = tid; i < 24 * 32; i += 256) {
    int d = i >> 5, seg = i & 31;
    *(uint4*)&kl[d * 256 + seg * 8] = *(const uint4*)(kp + (size_t)d * HW + seg * 8);
  }

  // dwconv 48 channels in 4 chunks of 12
  for (int chunk = 0; chunk < 4; ++chunk) {
    __syncthreads();   // protect stage from previous chunk's readers
    for (int i = tid; i < 12 * 3 * 32; i += 256) {
      int seg = i & 31, rr = i >> 5;
      int ch = rr / 3, ry = rr % 3;
      int cg = kvh * 96 + qh * 48 + chunk * 12 + ch;
      int hh = h + ry - 1;
      uint4 u = make_uint4(0u, 0u, 0u, 0u);
      if ((unsigned)hh < 256u)
        u = *(const uint4*)(y + (size_t)(b * OYC + cg) * HW + hh * 256 + seg * 8);
      *(uint4*)&stage[(ch * 3 + ry) * 256 + seg * 8] = u;
    }
    __syncthreads();
    for (int i = tid; i < 384; i += 256) {
      int ch = i >> 5, cg = i & 31;
      int c0 = cg * 8;
      int cgl = kvh * 96 + qh * 48 + chunk * 12 + ch;
      const float* wp = qdw + cgl * 9;
      float o[8];
#pragma unroll
      for (int j = 0; j < 8; ++j) o[j] = 0.f;
#pragma unroll
      for (int ry = 0; ry < 3; ++ry) {
        const __hip_bfloat16* rb = &stage[(ch * 3 + ry) * 256];
        float v[8];
        unpack8(*(const uint4*)&rb[c0], v);
        float vl = (c0 > 0)       ? bf2f(rb[c0 - 1]) : 0.f;
        float vr = (c0 + 8 < 256) ? bf2f(rb[c0 + 8]) : 0.f;
        float wl = wp[ry * 3], wm = wp[ry * 3 + 1], wr = wp[ry * 3 + 2];
        o[0] = fmaf(wl, vl, fmaf(wm, v[0], fmaf(wr, v[1], o[0])));
#pragma unroll
        for (int j = 1; j < 7; ++j)
          o[j] = fmaf(wl, v[j-1], fmaf(wm, v[j], fmaf(wr, v[j+1], o[j])));
        o[7] = fmaf(wl, v[6], fmaf(wm, v[7], fmaf(wr, vr, o[7])));
      }
      BF8 t;
#pragma unroll
      for (int j = 0; j < 8; ++j) t.h[j] = __float2bfloat16(o[j]);
      *(uint4*)&ql[(chunk * 12 + ch) * QP2 + c0] = t.u;
    }
  }
  __syncthreads();   // ql + kl complete

  // sum(q^2) per channel
  if (tid < 48) {
    float s = 0.f;
    for (int n = 0; n < 256; n += 8) {
      float f[8];
      unpack8(*(const uint4*)&ql[tid * QP2 + n], f);
#pragma unroll
      for (int e = 0; e < 8; ++e) s += f[e] * f[e];
    }
    atomicAdd(&qss[b * 192 + kvh * 96 + qh * 48 + tid], s);
  }

  // QK^T partials: thread = (nhalf, ccg(16) x dg(8)) -> 3x3 tile over 128 n
  int nhalf = tid >> 7, r = tid & 127;
  int ccg = r >> 3, dg = r & 7;
  int cc0 = ccg * 3, d0 = dg * 3;
  float acc[9];
#pragma unroll
  for (int i = 0; i < 9; ++i) acc[i] = 0.f;
  for (int n = nhalf * 128; n < nhalf * 128 + 128; n += 8) {
    float a[3][8], bv[3][8];
#pragma unroll
    for (int i = 0; i < 3; ++i) unpack8(*(const uint4*)&ql[(cc0 + i) * QP2 + n], a[i]);
#pragma unroll
    for (int j = 0; j < 3; ++j) unpack8(*(const uint4*)&kl[(d0 + j) * 256 + n], bv[j]);
#pragma unroll
    for (int i = 0; i < 3; ++i)
#pragma unroll
      for (int j = 0; j < 3; ++j)
#pragma unroll
        for (int e = 0; e < 8; ++e)
          acc[i * 3 + j] = fmaf(a[i][e], bv[j][e], acc[i * 3 + j]);
  }
  if (nhalf == 1) {
#pragma unroll
    for (int i = 0; i < 9; ++i) red[r * 9 + i] = acc[i];
  }
  __syncthreads();
  if (nhalf == 0) {
#pragma unroll
    for (int i = 0; i < 9; ++i) acc[i] += red[r * 9 + i];
#pragma unroll
    for (int i = 0; i < 3; ++i)
#pragma unroll
      for (int j = 0; j < 3; ++j) {
        int cc = qh * 48 + cc0 + i, d = d0 + j;
        int head = kvh * 4 + cc / 24, cp = cc % 24;
        atomicAdd(&attn[(((b * 8 + head) * 24) + cp) * 24 + d], acc[i * 3 + j]);
      }
  }
}

// ============================================================================
// K4: l2norm scaling + temperature + softmax, then fold proj_w through attn:
//     Mt[b][j=kvh*24+d][o] = sum_cc proj[o][kvh*96+cc] * attnS[kvh*96+cc][d]
// ============================================================================
__global__ void k_attn_final(const float* __restrict__ attn, const float* __restrict__ qss,
                             const float* __restrict__ kss, const float* __restrict__ temp,
                             const float* __restrict__ projw, float* __restrict__ Mt) {
  int b = blockIdx.x;
  int t = threadIdx.x;
  __shared__ float as_[96 * 25];
  float acc[48];
#pragma unroll
  for (int j = 0; j < 48; ++j) acc[j] = 0.f;
  for (int kvh = 0; kvh < 2; ++kvh) {
    __syncthreads();
    if (t < 96) {
      int row = kvh * 96 + t;           // global q channel
      int h = row / 24, cp = row % 24;
      float rq = 1.f / fmaxf(sqrtf(qss[b * 192 + row]), 1e-12f);
      float tp = temp[h];
      float lg[24]; float mx = -1e30f;
#pragma unroll
      for (int d = 0; d < 24; ++d) {
        float rk = 1.f / fmaxf(sqrtf(kss[b * 48 + kvh * 24 + d]), 1e-12f);
        float l = attn[(((b * 8 + h) * 24) + cp) * 24 + d] * rq * rk * tp;
        lg[d] = l; mx = fmaxf(mx, l);
      }
      float s = 0.f;
#pragma unroll
      for (int d = 0; d < 24; ++d) { lg[d] = __expf(lg[d] - mx); s += lg[d]; }
      float inv = 1.f / s;
#pragma unroll
      for (int d = 0; d < 24; ++d) as_[t * 25 + d] = lg[d] * inv;
    }
    __syncthreads();
    if (t < 192) {
      for (int cc = 0; cc < 96; ++cc) {
        float pw = projw[t * 192 + kvh * 96 + cc];
        const float* ar = &as_[cc * 25];
#pragma unroll
        for (int d = 0; d < 24; ++d) acc[kvh * 24 + d] = fmaf(pw, ar[d], acc[kvh * 24 + d]);
      }
    }
  }
  if (t < 192) {
#pragma unroll
    for (int j = 0; j < 48; ++j) Mt[((size_t)b * 48 + j) * 192 + t] = acc[j];
  }
}

// ============================================================================
// K5: out[b][o][n] = sum_j Mt[b][j][o] * v[b][j][n]   (fp32 output)
// ============================================================================
__global__ __launch_bounds__(256) void k_out(const __hip_bfloat16* __restrict__ vbuf,
                                             const float* __restrict__ Mt,
                                             float* __restrict__ out) {
  __shared__ float lv[48 * 64];
  int bid = blockIdx.x;
  int b  = bid >> 10;
  int n0 = (bid & 1023) * 64;
  int tid = threadIdx.x;
  const __hip_bfloat16* vb = vbuf + (size_t)b * 48 * HW + n0;
  for (int i = tid; i < 48 * 64; i += 256) {
    int c = i >> 6, tn = i & 63;
    lv[i] = bf2f(vb[(size_t)c * HW + tn]);
  }
  __syncthreads();
  int wave = __builtin_amdgcn_readfirstlane(tid >> 6);
  int tn = tid & 63;
  const float* mb = Mt + (size_t)b * 48 * 192;
  for (int ch = 0; ch < 2; ++ch) {
    int o0 = wave * 48 + ch * 24;
    float acc[24];
#pragma unroll
    for (int j = 0; j < 24; ++j) acc[j] = 0.f;
    for (int c = 0; c < 48; ++c) {
      float xv = lv[c * 64 + tn];
#pragma unroll
      for (int j = 0; j < 24; ++j) acc[j] = fmaf(mb[c * 192 + o0 + j], xv, acc[j]);
    }
    float* op = out + ((size_t)b * 192 + o0) * HW + n0 + tn;
#pragma unroll
    for (int j = 0; j < 24; ++j) op[(size_t)j * HW] = acc[j];
  }
}

// ============================================================================
// ws layout (float offsets):
//  0        qss   [4*192]      = 768
//  768      kss   [4*48]       = 192
//  960      attn  [4*8*24*24]  = 18432
//  19392    Mt    [4*48*192]   = 36864
//  56256    bias  [288]
//  56544    AF  bf16 [288*192] (= 27648 float slots)
//  111872   y   bf16 [4*288*HW]
//  37860608 kbuf bf16 [4*48*HW]
//  44152064 vbuf bf16 [4*48*HW]
// ============================================================================
extern "C" void kernel_launch(void* const* d_in, const int* in_sizes, int n_in,
                              void* d_out, int out_size, void* d_ws, size_t ws_size,
                              hipStream_t stream) {
  const float* x     = (const float*)d_in[0];
  const float* ln_w  = (const float*)d_in[1];
  const float* ln_b  = (const float*)d_in[2];
  const float* q_w   = (const float*)d_in[3];
  const float* q_dw  = (const float*)d_in[4];
  const float* kv_w  = (const float*)d_in[5];
  const float* kv_dw = (const float*)d_in[6];
  const float* projw = (const float*)d_in[7];
  const float* temp  = (const float*)d_in[8];
  float* out = (float*)d_out;
  float* wsf = (float*)d_ws;

  float* qss  = wsf;
  float* kss  = wsf + 768;
  float* attn = wsf + 960;
  float* Mt   = wsf + 19392;
  float* bias = wsf + 56256;
  __hip_bfloat16* AF = (__hip_bfloat16*)(wsf + 56544);
  __hip_bfloat16* y    = (__hip_bfloat16*)(wsf + 111872);
  __hip_bfloat16* kbuf = (__hip_bfloat16*)(wsf + 37860608);
  __hip_bfloat16* vbuf = (__hip_bfloat16*)(wsf + 44152064);

  hipMemsetAsync(wsf, 0, 19392 * sizeof(float), stream);  // qss+kss+attn accumulators
  hipLaunchKernelGGL(k_prep, dim3(1), dim3(256), 0, stream, q_w, kv_w, ln_w, ln_b, AF, bias);
  hipLaunchKernelGGL(k_conv1, dim3(NB * 1024), dim3(256), 0, stream, x, AF, bias, y);
  hipLaunchKernelGGL(k_dwkv, dim3(NB * 96 * 16), dim3(256), 0, stream, y, kv_dw, kbuf, vbuf, kss);
  hipLaunchKernelGGL(k_dwq_attn, dim3(NB * 2 * 2 * 256), dim3(256), 0, stream, y, q_dw, kbuf, qss, attn);
  hipLaunchKernelGGL(k_attn_final, dim3(NB), dim3(256), 0, stream, attn, qss, kss, temp, projw, Mt);
  hipLaunchKernelGGL(k_out, dim3(NB * 1024), dim3(256), 0, stream, vbuf, Mt, out);
}